// Round 1
// baseline (191.669 us; speedup 1.0000x reference)
//
#include <hip/hip_runtime.h>
#include <hip/hip_bf16.h>
#include <cstddef>

// Problem constants (from reference): X=4096, H=1024, L=8, VT=512, ET=1024
// z = [input_x(4096) ; h_prev[l](1024) ; prev_layer(1024)]  -> 6144 cols
// Wg: (L, 4H, 6144) row-major fp32. Gates order: i, f, o, s.

#define XDIM 4096
#define HDIM 1024
#define LNUM 8
#define ZDIM 6144
#define ZPAR 5120   // X + H (scan-independent part)
#define VT 512
#define ET 1024

__device__ __forceinline__ float sigmoidf_(float v) {
    return 1.0f / (1.0f + expf(-v));
}

// ---------------------------------------------------------------------------
// Kernel A: partial[l*4096+g] = bg[row] + Wg[row, 0:5120] . [x ; h_prev[l]]
// One wave (64 lanes) per row; 4 rows per 256-thread block; z staged in LDS.
// ---------------------------------------------------------------------------
__global__ __launch_bounds__(256) void partial_gates_kernel(
    const float* __restrict__ x,
    const float* __restrict__ hprev,
    const float* __restrict__ Wg,
    const float* __restrict__ bg,
    float* __restrict__ partial)
{
    __shared__ float z[ZPAR];  // 20 KB

    const int block_row0 = blockIdx.x * 4;
    const int l = block_row0 >> 12;   // row / 4096 (4 rows never straddle layers)

    // stage z = [x ; h_prev[l]] into LDS with float4 loads
    for (int i = threadIdx.x; i < XDIM / 4; i += blockDim.x)
        reinterpret_cast<float4*>(z)[i] = reinterpret_cast<const float4*>(x)[i];
    for (int i = threadIdx.x; i < HDIM / 4; i += blockDim.x)
        reinterpret_cast<float4*>(z + XDIM)[i] =
            reinterpret_cast<const float4*>(hprev + l * HDIM)[i];
    __syncthreads();

    const int wave = threadIdx.x >> 6;
    const int lane = threadIdx.x & 63;
    const int row  = block_row0 + wave;

    const float4* __restrict__ Wrow =
        reinterpret_cast<const float4*>(Wg + (size_t)row * ZDIM);
    const float4* __restrict__ z4 = reinterpret_cast<const float4*>(z);

    float acc = 0.0f;
    // 5120 floats = 1280 float4; 64 lanes -> 20 passes
    #pragma unroll 4
    for (int p = 0; p < 20; ++p) {
        float4 w  = Wrow[p * 64 + lane];
        float4 zv = z4[p * 64 + lane];
        acc += w.x * zv.x + w.y * zv.y + w.z * zv.z + w.w * zv.w;
    }
    #pragma unroll
    for (int off = 32; off > 0; off >>= 1)
        acc += __shfl_down(acc, off, 64);

    if (lane == 0)
        partial[row] = acc + bg[row];
}

// ---------------------------------------------------------------------------
// Kernel B (per layer): finish gates with the carry part, apply LSTM cell.
// One wave per h (computes all 4 gate rows); 4 h per block; grid = 256 blocks.
// ---------------------------------------------------------------------------
__global__ __launch_bounds__(256) void layer_step_kernel(
    const float* __restrict__ Wg,
    const float* __restrict__ partial,
    const float* __restrict__ old_state,
    const float* __restrict__ hidden_prev,   // hidden of previous layer (or unused)
    float* __restrict__ hidden_out,          // hidden[l] (H floats)
    int l, int has_prev)
{
    __shared__ float hp[HDIM];  // 4 KB

    if (has_prev) {
        // 256 threads x float4 = 1024 floats
        reinterpret_cast<float4*>(hp)[threadIdx.x] =
            reinterpret_cast<const float4*>(hidden_prev)[threadIdx.x];
    }
    __syncthreads();

    const int wave = threadIdx.x >> 6;
    const int lane = threadIdx.x & 63;
    const int h    = blockIdx.x * 4 + wave;

    const float4* __restrict__ hp4 = reinterpret_cast<const float4*>(hp);

    float g[4];
    #pragma unroll
    for (int q = 0; q < 4; ++q) {
        float acc = 0.0f;
        if (has_prev) {
            const size_t row = (size_t)l * 4096 + (size_t)q * HDIM + h;
            const float4* __restrict__ Wrow =
                reinterpret_cast<const float4*>(Wg + row * ZDIM + ZPAR);
            // 1024 floats = 256 float4; 64 lanes -> 4 passes
            #pragma unroll
            for (int p = 0; p < 4; ++p) {
                float4 w  = Wrow[p * 64 + lane];
                float4 zv = hp4[p * 64 + lane];
                acc += w.x * zv.x + w.y * zv.y + w.z * zv.z + w.w * zv.w;
            }
        }
        #pragma unroll
        for (int off = 32; off > 0; off >>= 1)
            acc += __shfl_down(acc, off, 64);
        g[q] = acc + partial[(size_t)l * 4096 + (size_t)q * HDIM + h];
    }

    if (lane == 0) {
        const float ig = sigmoidf_(g[0]);
        const float fg = sigmoidf_(g[1]);
        const float og = sigmoidf_(g[2]);
        const float sg = tanhf(g[3]);
        const float ns = fg * old_state[l * HDIM + h] + ig * sg;
        hidden_out[h] = og * tanhf(ns);
    }
}

// ---------------------------------------------------------------------------
// Kernel C: heads. rows [0,512) -> Wy/by -> out[0:512)
//           rows [512,1536) -> We/be -> out[512:1536)
// One wave per row; 4 rows per block; flat (8192 f32 = 32 KB) staged in LDS.
// ---------------------------------------------------------------------------
__global__ __launch_bounds__(256) void head_kernel(
    const float* __restrict__ Wy, const float* __restrict__ by,
    const float* __restrict__ We, const float* __restrict__ be,
    const float* __restrict__ flat,
    float* __restrict__ out)
{
    __shared__ float z[LNUM * HDIM];  // 32 KB

    for (int i = threadIdx.x; i < (LNUM * HDIM) / 4; i += blockDim.x)
        reinterpret_cast<float4*>(z)[i] = reinterpret_cast<const float4*>(flat)[i];
    __syncthreads();

    const int wave = threadIdx.x >> 6;
    const int lane = threadIdx.x & 63;
    const int row  = blockIdx.x * 4 + wave;

    const float* __restrict__ W;
    float b;
    if (row < VT) { W = Wy + (size_t)row * (LNUM * HDIM);          b = by[row]; }
    else          { W = We + (size_t)(row - VT) * (LNUM * HDIM);   b = be[row - VT]; }

    const float4* __restrict__ W4 = reinterpret_cast<const float4*>(W);
    const float4* __restrict__ z4 = reinterpret_cast<const float4*>(z);

    float acc = 0.0f;
    // 8192 floats = 2048 float4; 64 lanes -> 32 passes
    #pragma unroll 4
    for (int p = 0; p < 32; ++p) {
        float4 w  = W4[p * 64 + lane];
        float4 zv = z4[p * 64 + lane];
        acc += w.x * zv.x + w.y * zv.y + w.z * zv.z + w.w * zv.w;
    }
    #pragma unroll
    for (int off = 32; off > 0; off >>= 1)
        acc += __shfl_down(acc, off, 64);

    if (lane == 0)
        out[row] = acc + b;
}

// ---------------------------------------------------------------------------
extern "C" void kernel_launch(void* const* d_in, const int* in_sizes, int n_in,
                              void* d_out, int out_size, void* d_ws, size_t ws_size,
                              hipStream_t stream)
{
    const float* x         = (const float*)d_in[0];  // (4096,)
    const float* hprev     = (const float*)d_in[1];  // (8,1024)
    const float* Wg        = (const float*)d_in[2];  // (8,4096,6144)
    const float* bg        = (const float*)d_in[3];  // (8,4096)
    const float* old_state = (const float*)d_in[4];  // (8,1024)
    const float* Wy        = (const float*)d_in[5];  // (512,8192)
    const float* by        = (const float*)d_in[6];  // (512,)
    const float* We        = (const float*)d_in[7];  // (1024,8192)
    const float* be        = (const float*)d_in[8];  // (1024,)
    float* out = (float*)d_out;                      // 512 + 1024 = 1536 fp32

    float* partial = (float*)d_ws;                   // 32768 f32 = 128 KB
    float* hidden  = partial + LNUM * 4096;          // 8192  f32 = 32 KB

    // 1) scan-independent part of all gates, all layers in parallel
    partial_gates_kernel<<<8192, 256, 0, stream>>>(x, hprev, Wg, bg, partial);

    // 2) sequential scan over layers (layer 0 has zero carry -> skip GEMV)
    for (int l = 0; l < LNUM; ++l) {
        layer_step_kernel<<<256, 256, 0, stream>>>(
            Wg, partial, old_state,
            (l > 0) ? (hidden + (size_t)(l - 1) * HDIM) : hidden /*unused*/,
            hidden + (size_t)l * HDIM, l, (l > 0) ? 1 : 0);
    }

    // 3) heads
    head_kernel<<<(VT + ET) / 4, 256, 0, stream>>>(Wy, by, We, be, hidden, out);
}